// Round 9
// baseline (627.837 us; speedup 1.0000x reference)
//
#include <hip/hip_runtime.h>

#define NTOK 262144L

typedef __attribute__((ext_vector_type(4))) float f32x4;
typedef __attribute__((ext_vector_type(8))) short bf16x8;   // 8 x bf16 (4 VGPRs)

static __device__ __forceinline__ unsigned short f2bf(float f) {
  unsigned int u = __builtin_bit_cast(unsigned int, f);
  u += 0x7fffu + ((u >> 16) & 1u);          // round-nearest-even
  return (unsigned short)(u >> 16);
}

static __device__ __forceinline__ unsigned cvtpk(float lo, float hi) {
  unsigned r;
  asm("v_cvt_pk_bf16_f32 %0, %1, %2" : "=v"(r) : "v"(lo), "v"(hi));
  return r;
}

union U8 { unsigned u[4]; bf16x8 v; };

// H (bf16, 256B rows = 16 x 16B slots): byte-XOR swizzle key
static __device__ __forceinline__ int swzh(int row) {
  return ((row & 8) << 1) | ((row & 6) << 5);
}

// ---- pre-pack all weights fp32 -> bf16 in MFMA B-fragment order ----
// W1 region: [e][kt=16][ct=8][lane=64][j=8]  (k = kt*32 + (lane>>4)*8 + j, col = ct*16 + (lane&15))
// W2 region: [e][kt=4 ][ct=8][lane=64][j=8]
__global__ void pack_w(const float* __restrict__ Wt1, const float* __restrict__ Wa1,
                       const float* __restrict__ Wv1, const float* __restrict__ Wt2,
                       const float* __restrict__ Wa2, const float* __restrict__ Wv2,
                       unsigned short* __restrict__ pk) {
  int idx = blockIdx.x * 256 + threadIdx.x;
  if (idx >= 245760) return;
  float v;
  if (idx < 196608) {
    int j = idx & 7, l = (idx >> 3) & 63, ct = (idx >> 9) & 7, kt = (idx >> 12) & 15, e = idx >> 16;
    const float* W = (e == 0) ? Wt1 : (e == 1) ? Wa1 : Wv1;
    v = W[(kt * 32 + ((l >> 4) * 8) + j) * 128 + ct * 16 + (l & 15)];
  } else {
    int i2 = idx - 196608;
    int j = i2 & 7, l = (i2 >> 3) & 63, ct = (i2 >> 9) & 7, kt = (i2 >> 12) & 3, e = i2 >> 14;
    const float* W = (e == 0) ? Wt2 : (e == 1) ? Wa2 : Wv2;
    v = W[(kt * 32 + ((l >> 4) * 8) + j) * 128 + ct * 16 + (l & 15)];
  }
  pk[idx] = f2bf(v);
}

// store relu(acc) (4 rows 4g..4g+3, one col) into swizzled bf16 H tile
static __device__ __forceinline__ void stH(char* Hb, int g, int col, int rbase, f32x4 a) {
  #pragma unroll
  for (int rp = 0; rp < 2; ++rp) {
    int r0 = rbase + 4 * g + 2 * rp;
    unsigned p = cvtpk(fmaxf(a[2 * rp], 0.f), fmaxf(a[2 * rp + 1], 0.f));
    int a0 = r0 * 256 + ((((col >> 3) << 4)) ^ swzh(r0)) + (col & 7) * 2;
    int a1 = (r0 + 1) * 256 + ((((col >> 3) << 4)) ^ swzh(r0 + 1)) + (col & 7) * 2;
    *(unsigned short*)(Hb + a0) = (unsigned short)p;
    *(unsigned short*)(Hb + a1) = (unsigned short)(p >> 16);
  }
}

static __device__ __forceinline__ bf16x8 ldH(const char* hb, int row, int kt, int g) {
  return *(const bf16x8*)(hb + row * 256 + ((((kt * 4 + g) << 4)) ^ swzh(row)));
}

// Block: 32 rows x 128 cols, 512 thr = 8 waves; wave w -> cols [16w, 16w+16).
// Per-wave live state ~105 VGPR (acc 24 + W 24 + A 24 + misc) -> fits the
// 128-reg budget of __launch_bounds__(512,4); NO spills (R5/R7/R8 lesson).
// Layer 1 barrier-free (A direct from global, depth-1 prefetch of W and A);
// exactly one __syncthreads (H redistribution); merged 3-expert layer 2.
__global__ __launch_bounds__(512, 4) void mlp3(
    const float* __restrict__ X, const unsigned short* __restrict__ pk,
    const float* __restrict__ bt1, const float* __restrict__ bt2,
    const float* __restrict__ ba1, const float* __restrict__ ba2,
    const float* __restrict__ bv1, const float* __restrict__ bv2,
    float* __restrict__ out) {
  __shared__ unsigned short H0[32 * 128];   // 8 KiB
  __shared__ unsigned short H1[32 * 128];   // 8 KiB
  __shared__ unsigned short H2[32 * 128];   // 8 KiB
  const int t = threadIdx.x;
  const long brow = (long)blockIdx.x * 32;
  const int lane = t & 63;
  const int w = t >> 6;          // 0..7
  const int l15 = lane & 15;
  const int g = lane >> 4;

  // routing flags -> 8-bit mask immediately (1 VGPR persists)
  unsigned fmask = 0;
  #pragma unroll
  for (int rt = 0; rt < 2; ++rt)
    #pragma unroll
    for (int r = 0; r < 4; ++r) {
      float fv = X[(brow + rt * 16 + 4 * g + r) * 512 + 511];
      if (fv != 0.f) fmask |= 1u << (rt * 4 + r);
    }

  // layer-1 accumulators: 3 experts x rt=2 x ct=1
  f32x4 at[2], aa[2], av[2];
  {
    float b0 = bt1[w * 16 + l15];
    float b1v = ba1[w * 16 + l15];
    float b2v = bv1[w * 16 + l15];
    #pragma unroll
    for (int rt = 0; rt < 2; ++rt) {
      at[rt] = (f32x4){b0, b0, b0, b0};
      aa[rt] = (f32x4){b1v, b1v, b1v, b1v};
      av[rt] = (f32x4){b2v, b2v, b2v, b2v};
    }
  }

  // per-lane A bases: rows brow+l15, brow+l15+16; k-offset g*8
  const float* __restrict__ A0 = X + (brow + l15) * 512 + g * 8;
  const float* __restrict__ A1 = A0 + 16 * 512;

  // prefetch kt=0 (W: 3 frags for this wave's 16 cols; A: fp32 x8 per rt)
  bf16x8 wt = *(const bf16x8*)(pk + ((0 * 8 + w) << 9) + (lane << 3));
  bf16x8 wa = *(const bf16x8*)(pk + 65536 + ((0 * 8 + w) << 9) + (lane << 3));
  bf16x8 wv = *(const bf16x8*)(pk + 131072 + ((0 * 8 + w) << 9) + (lane << 3));
  f32x4 x0a = *(const f32x4*)(A0);
  f32x4 x0b = *(const f32x4*)(A0 + 4);
  f32x4 x1a = *(const f32x4*)(A1);
  f32x4 x1b = *(const f32x4*)(A1 + 4);

  // ---- fused layer-1 K loop: barrier-free, depth-1 pipeline ----
  #pragma unroll 1
  for (int kt = 0; kt < 16; ++kt) {
    bf16x8 ft = wt, fa = wa, fv = wv;
    f32x4 c0a = x0a, c0b = x0b, c1a = x1a, c1b = x1b;
    if (kt < 15) {   // issue kt+1 loads before kt's MFMA cluster
      const int wo = (((kt + 1) * 8 + w) << 9) + (lane << 3);
      wt = *(const bf16x8*)(pk + wo);
      wa = *(const bf16x8*)(pk + 65536 + wo);
      wv = *(const bf16x8*)(pk + 131072 + wo);
      const float* p0 = A0 + (kt + 1) * 32;
      const float* p1 = A1 + (kt + 1) * 32;
      x0a = *(const f32x4*)p0;
      x0b = *(const f32x4*)(p0 + 4);
      x1a = *(const f32x4*)p1;
      x1b = *(const f32x4*)(p1 + 4);
    }
    U8 u0, u1;
    u0.u[0] = cvtpk(c0a[0], c0a[1]);
    u0.u[1] = cvtpk(c0a[2], c0a[3]);
    u0.u[2] = cvtpk(c0b[0], c0b[1]);
    u0.u[3] = cvtpk(c0b[2], c0b[3]);
    u1.u[0] = cvtpk(c1a[0], c1a[1]);
    u1.u[1] = cvtpk(c1a[2], c1a[3]);
    u1.u[2] = cvtpk(c1b[0], c1b[1]);
    u1.u[3] = cvtpk(c1b[2], c1b[3]);
    __builtin_amdgcn_s_setprio(1);
    at[0] = __builtin_amdgcn_mfma_f32_16x16x32_bf16(u0.v, ft, at[0], 0, 0, 0);
    aa[0] = __builtin_amdgcn_mfma_f32_16x16x32_bf16(u0.v, fa, aa[0], 0, 0, 0);
    av[0] = __builtin_amdgcn_mfma_f32_16x16x32_bf16(u0.v, fv, av[0], 0, 0, 0);
    at[1] = __builtin_amdgcn_mfma_f32_16x16x32_bf16(u1.v, ft, at[1], 0, 0, 0);
    aa[1] = __builtin_amdgcn_mfma_f32_16x16x32_bf16(u1.v, fa, aa[1], 0, 0, 0);
    av[1] = __builtin_amdgcn_mfma_f32_16x16x32_bf16(u1.v, fv, av[1], 0, 0, 0);
    __builtin_amdgcn_s_setprio(0);
  }

  // ---- relu + write 3 hidden tiles; the ONLY barrier ----
  {
    const int col = w * 16 + l15;
    #pragma unroll
    for (int rt = 0; rt < 2; ++rt) {
      stH((char*)H0, g, col, rt * 16, at[rt]);
      stH((char*)H1, g, col, rt * 16, aa[rt]);
      stH((char*)H2, g, col, rt * 16, av[rt]);
    }
  }
  __syncthreads();

  // ---- layer 2: 3 experts merged (3x ILP) ----
  f32x4 k2[2], a2[2], v2[2];
  {
    float b0 = bt2[w * 16 + l15];
    float b1v = ba2[w * 16 + l15];
    float b2v = bv2[w * 16 + l15];
    #pragma unroll
    for (int rt = 0; rt < 2; ++rt) {
      k2[rt] = (f32x4){b0, b0, b0, b0};
      a2[rt] = (f32x4){b1v, b1v, b1v, b1v};
      v2[rt] = (f32x4){b2v, b2v, b2v, b2v};
    }
  }
  const unsigned short* __restrict__ W2 = pk + 196608;
  #pragma unroll
  for (int kt = 0; kt < 4; ++kt) {
    const int wo = ((kt * 8 + w) << 9) + (lane << 3);
    bf16x8 wt2 = *(const bf16x8*)(W2 + wo);
    bf16x8 wa2 = *(const bf16x8*)(W2 + 16384 + wo);
    bf16x8 wv2 = *(const bf16x8*)(W2 + 32768 + wo);
    #pragma unroll
    for (int rt = 0; rt < 2; ++rt) {
      bf16x8 h0 = ldH((const char*)H0, rt * 16 + l15, kt, g);
      bf16x8 h1 = ldH((const char*)H1, rt * 16 + l15, kt, g);
      bf16x8 h2 = ldH((const char*)H2, rt * 16 + l15, kt, g);
      k2[rt] = __builtin_amdgcn_mfma_f32_16x16x32_bf16(h0, wt2, k2[rt], 0, 0, 0);
      a2[rt] = __builtin_amdgcn_mfma_f32_16x16x32_bf16(h1, wa2, a2[rt], 0, 0, 0);
      v2[rt] = __builtin_amdgcn_mfma_f32_16x16x32_bf16(h2, wv2, v2[rt], 0, 0, 0);
    }
  }

  // ---- select + batched stores ----
  float* __restrict__ ov = out + NTOK * 128;
  const int col = w * 16 + l15;
  #pragma unroll
  for (int rt = 0; rt < 2; ++rt)
    #pragma unroll
    for (int r = 0; r < 4; ++r) {
      long row = brow + rt * 16 + 4 * g + r;
      float pi = ((fmask >> (rt * 4 + r)) & 1u) ? a2[rt][r] : k2[rt][r];
      out[row * 128 + col] = pi;
      ov[row * 128 + col] = fmaxf(v2[rt][r], 0.f);
    }
}

extern "C" void kernel_launch(void* const* d_in, const int* in_sizes, int n_in,
                              void* d_out, int out_size, void* d_ws, size_t ws_size,
                              hipStream_t stream) {
  const float* X   = (const float*)d_in[0];
  const float* Wt1 = (const float*)d_in[1];
  const float* bt1 = (const float*)d_in[2];
  const float* Wt2 = (const float*)d_in[3];
  const float* bt2 = (const float*)d_in[4];
  const float* Wa1 = (const float*)d_in[5];
  const float* ba1 = (const float*)d_in[6];
  const float* Wa2 = (const float*)d_in[7];
  const float* ba2 = (const float*)d_in[8];
  const float* Wv1 = (const float*)d_in[9];
  const float* bv1 = (const float*)d_in[10];
  const float* Wv2 = (const float*)d_in[11];
  const float* bv2 = (const float*)d_in[12];
  unsigned short* pk = (unsigned short*)d_ws;   // 245760 bf16 = 480 KiB packed weights

  pack_w<<<960, 256, 0, stream>>>(Wt1, Wa1, Wv1, Wt2, Wa2, Wv2, pk);
  mlp3<<<8192, 512, 0, stream>>>(X, pk, bt1, bt2, ba1, ba2, bv1, bv2, (float*)d_out);
}

// Round 10
// 501.778 us; speedup vs baseline: 1.2512x; 1.2512x over previous
//
#include <hip/hip_runtime.h>

#define NTOK 262144L

typedef __attribute__((ext_vector_type(4))) float f32x4;
typedef __attribute__((ext_vector_type(8))) short bf16x8;   // 8 x bf16 (4 VGPRs)

static __device__ __forceinline__ unsigned short f2bf(float f) {
  unsigned int u = __builtin_bit_cast(unsigned int, f);
  u += 0x7fffu + ((u >> 16) & 1u);          // round-nearest-even
  return (unsigned short)(u >> 16);
}

static __device__ __forceinline__ unsigned cvtpk(float lo, float hi) {
  unsigned r;
  asm("v_cvt_pk_bf16_f32 %0, %1, %2" : "=v"(r) : "v"(lo), "v"(hi));
  return r;
}

union U8 { unsigned u[4]; bf16x8 v; };

// ---- pre-pack all weights fp32 -> bf16 in MFMA fragment order (unchanged) ----
// W1 region: [e][kt=16][ct=8][lane=64][j=8]  (k = kt*32 + (lane>>4)*8 + j, col = ct*16 + (lane&15))
// W2 region: [e][kt=4 ][ct=8][lane=64][j=8]
__global__ void pack_w(const float* __restrict__ Wt1, const float* __restrict__ Wa1,
                       const float* __restrict__ Wv1, const float* __restrict__ Wt2,
                       const float* __restrict__ Wa2, const float* __restrict__ Wv2,
                       unsigned short* __restrict__ pk) {
  int idx = blockIdx.x * 256 + threadIdx.x;
  if (idx >= 245760) return;
  float v;
  if (idx < 196608) {
    int j = idx & 7, l = (idx >> 3) & 63, ct = (idx >> 9) & 7, kt = (idx >> 12) & 15, e = idx >> 16;
    const float* W = (e == 0) ? Wt1 : (e == 1) ? Wa1 : Wv1;
    v = W[(kt * 32 + ((l >> 4) * 8) + j) * 128 + ct * 16 + (l & 15)];
  } else {
    int i2 = idx - 196608;
    int j = i2 & 7, l = (i2 >> 3) & 63, ct = (i2 >> 9) & 7, kt = (i2 >> 12) & 3, e = i2 >> 14;
    const float* W = (e == 0) ? Wt2 : (e == 1) ? Wa2 : Wv2;
    v = W[(kt * 32 + ((l >> 4) * 8) + j) * 128 + ct * 16 + (l & 15)];
  }
  pk[idx] = f2bf(v);
}

// SWAPPED-OPERAND design: D = mfma(A = W-frag, B = X-frag) -> lane&15 = x-row.
// Wave = 16 rows x all 128 cols; acc[ct][r] = H[row l15][col 16*ct + 4*g + r].
// H stays lane-local -> ZERO __syncthreads. Wave-private LDS slab re-shapes
// acc into layer-2 B-frags (own-wave ds_write -> ds_read, lgkmcnt only).
__global__ __launch_bounds__(256, 3) void mlp3(
    const float* __restrict__ X, const unsigned short* __restrict__ pk,
    const float* __restrict__ bt1, const float* __restrict__ bt2,
    const float* __restrict__ ba1, const float* __restrict__ ba2,
    const float* __restrict__ bv1, const float* __restrict__ bv2,
    float* __restrict__ out) {
  __shared__ char Hs[4][3 * 4096];   // 48 KiB: per-wave-private H (3 experts x 16 rows x 256B)
  const int t = threadIdx.x;
  const int lane = t & 63;
  const int w = t >> 6;
  const int l15 = lane & 15;
  const int g = lane >> 4;
  const long myrow = (long)blockIdx.x * 64 + w * 16 + l15;
  const float* __restrict__ Xr = X + myrow * 512;
  const int hxor = (l15 & 7) << 4;   // 16B-slot XOR key (row-determined, write & read)
  char* const hw = Hs[w];

  const float flag = Xr[511];        // this lane's row routing flag

  // ---- layer-1 accumulators [expert][ct], bias-initialized via direct f32x4 ----
  f32x4 acc0[8], acc1[8], acc2[8];
  #pragma unroll
  for (int ct = 0; ct < 8; ++ct) {
    acc0[ct] = *(const f32x4*)(bt1 + ct * 16 + 4 * g);
    acc1[ct] = *(const f32x4*)(ba1 + ct * 16 + 4 * g);
    acc2[ct] = *(const f32x4*)(bv1 + ct * 16 + 4 * g);
  }

  // X B-frag: 8 floats at row l15, k = kt*32 + g*8 (prefetched one kt ahead)
  f32x4 xa = *(const f32x4*)(Xr + g * 8);
  f32x4 xb = *(const f32x4*)(Xr + g * 8 + 4);

  // ---- fused layer-1: barrier-free K loop ----
  #pragma unroll 1
  for (int kt = 0; kt < 16; ++kt) {
    U8 u;
    u.u[0] = cvtpk(xa[0], xa[1]);
    u.u[1] = cvtpk(xa[2], xa[3]);
    u.u[2] = cvtpk(xb[0], xb[1]);
    u.u[3] = cvtpk(xb[2], xb[3]);
    if (kt < 15) {
      xa = *(const f32x4*)(Xr + (kt + 1) * 32 + g * 8);
      xb = *(const f32x4*)(Xr + (kt + 1) * 32 + g * 8 + 4);
    }
    const unsigned short* __restrict__ pb = pk + ((kt * 8) << 9) + (lane << 3);
    #pragma unroll
    for (int ct = 0; ct < 8; ++ct) {
      bf16x8 ft = *(const bf16x8*)(pb + (ct << 9));
      bf16x8 fa = *(const bf16x8*)(pb + 65536 + (ct << 9));
      bf16x8 fv = *(const bf16x8*)(pb + 131072 + (ct << 9));
      acc0[ct] = __builtin_amdgcn_mfma_f32_16x16x32_bf16(ft, u.v, acc0[ct], 0, 0, 0);
      acc1[ct] = __builtin_amdgcn_mfma_f32_16x16x32_bf16(fa, u.v, acc1[ct], 0, 0, 0);
      acc2[ct] = __builtin_amdgcn_mfma_f32_16x16x32_bf16(fv, u.v, acc2[ct], 0, 0, 0);
    }
  }

  // ---- relu + pack H into wave-private LDS (no barrier; own-wave deps only) ----
  const int hbase = l15 * 256;
  #pragma unroll
  for (int ct = 0; ct < 8; ++ct) {
    int off = hbase + ((32 * ct + 8 * g) ^ hxor);
    unsigned long long p0 =
        (unsigned long long)cvtpk(fmaxf(acc0[ct][0], 0.f), fmaxf(acc0[ct][1], 0.f)) |
        ((unsigned long long)cvtpk(fmaxf(acc0[ct][2], 0.f), fmaxf(acc0[ct][3], 0.f)) << 32);
    unsigned long long p1 =
        (unsigned long long)cvtpk(fmaxf(acc1[ct][0], 0.f), fmaxf(acc1[ct][1], 0.f)) |
        ((unsigned long long)cvtpk(fmaxf(acc1[ct][2], 0.f), fmaxf(acc1[ct][3], 0.f)) << 32);
    unsigned long long p2 =
        (unsigned long long)cvtpk(fmaxf(acc2[ct][0], 0.f), fmaxf(acc2[ct][1], 0.f)) |
        ((unsigned long long)cvtpk(fmaxf(acc2[ct][2], 0.f), fmaxf(acc2[ct][3], 0.f)) << 32);
    *(unsigned long long*)(hw + off) = p0;
    *(unsigned long long*)(hw + 4096 + off) = p1;
    *(unsigned long long*)(hw + 8192 + off) = p2;
  }

  // ---- layer 2: t and a together (2x ILP), then v; all swapped-MFMA ----
  const unsigned short* __restrict__ W2 = pk + 196608;
  f32x4 r0[8], r1[8];
  #pragma unroll
  for (int ct = 0; ct < 8; ++ct) {
    r0[ct] = *(const f32x4*)(bt2 + ct * 16 + 4 * g);
    r1[ct] = *(const f32x4*)(ba2 + ct * 16 + 4 * g);
  }
  #pragma unroll
  for (int s = 0; s < 4; ++s) {
    bf16x8 h0 = *(const bf16x8*)(hw + hbase + ((64 * s + 16 * g) ^ hxor));
    bf16x8 h1 = *(const bf16x8*)(hw + 4096 + hbase + ((64 * s + 16 * g) ^ hxor));
    const unsigned short* __restrict__ qb = W2 + ((s * 8) << 9) + (lane << 3);
    #pragma unroll
    for (int ct = 0; ct < 8; ++ct) {
      r0[ct] = __builtin_amdgcn_mfma_f32_16x16x32_bf16(
                   *(const bf16x8*)(qb + (ct << 9)), h0, r0[ct], 0, 0, 0);
      r1[ct] = __builtin_amdgcn_mfma_f32_16x16x32_bf16(
                   *(const bf16x8*)(qb + 16384 + (ct << 9)), h1, r1[ct], 0, 0, 0);
    }
  }

  // select + store pi (lane-uniform flag -> no per-element masking)
  {
    const bool sel = (flag != 0.f);
    float* __restrict__ op = out + myrow * 128;
    #pragma unroll
    for (int ct = 0; ct < 8; ++ct) {
      f32x4 r = sel ? r1[ct] : r0[ct];
      *(f32x4*)(op + ct * 16 + 4 * g) = r;
    }
  }

  // value head
  f32x4 rv[8];
  #pragma unroll
  for (int ct = 0; ct < 8; ++ct)
    rv[ct] = *(const f32x4*)(bv2 + ct * 16 + 4 * g);
  #pragma unroll
  for (int s = 0; s < 4; ++s) {
    bf16x8 h2 = *(const bf16x8*)(hw + 8192 + hbase + ((64 * s + 16 * g) ^ hxor));
    const unsigned short* __restrict__ qb = W2 + 32768 + ((s * 8) << 9) + (lane << 3);
    #pragma unroll
    for (int ct = 0; ct < 8; ++ct)
      rv[ct] = __builtin_amdgcn_mfma_f32_16x16x32_bf16(
                   *(const bf16x8*)(qb + (ct << 9)), h2, rv[ct], 0, 0, 0);
  }
  {
    float* __restrict__ ovp = out + NTOK * 128 + myrow * 128;
    #pragma unroll
    for (int ct = 0; ct < 8; ++ct) {
      f32x4 r = rv[ct];
      r[0] = fmaxf(r[0], 0.f); r[1] = fmaxf(r[1], 0.f);
      r[2] = fmaxf(r[2], 0.f); r[3] = fmaxf(r[3], 0.f);
      *(f32x4*)(ovp + ct * 16 + 4 * g) = r;
    }
  }
}

extern "C" void kernel_launch(void* const* d_in, const int* in_sizes, int n_in,
                              void* d_out, int out_size, void* d_ws, size_t ws_size,
                              hipStream_t stream) {
  const float* X   = (const float*)d_in[0];
  const float* Wt1 = (const float*)d_in[1];
  const float* bt1 = (const float*)d_in[2];
  const float* Wt2 = (const float*)d_in[3];
  const float* bt2 = (const float*)d_in[4];
  const float* Wa1 = (const float*)d_in[5];
  const float* ba1 = (const float*)d_in[6];
  const float* Wa2 = (const float*)d_in[7];
  const float* ba2 = (const float*)d_in[8];
  const float* Wv1 = (const float*)d_in[9];
  const float* bv1 = (const float*)d_in[10];
  const float* Wv2 = (const float*)d_in[11];
  const float* bv2 = (const float*)d_in[12];
  unsigned short* pk = (unsigned short*)d_ws;   // 245760 bf16 = 480 KiB packed weights

  pack_w<<<960, 256, 0, stream>>>(Wt1, Wa1, Wv1, Wt2, Wa2, Wv2, pk);
  mlp3<<<4096, 256, 0, stream>>>(X, pk, bt1, bt2, ba1, ba2, bv1, bv2, (float*)d_out);
}

// Round 11
// 304.088 us; speedup vs baseline: 2.0647x; 1.6501x over previous
//
#include <hip/hip_runtime.h>

#define NTOK 262144L

typedef __attribute__((ext_vector_type(4))) float f32x4;
typedef __attribute__((ext_vector_type(8))) short bf16x8;   // 8 x bf16 (4 VGPRs)

static __device__ __forceinline__ unsigned cvtpk(float lo, float hi) {
  unsigned r;
  asm("v_cvt_pk_bf16_f32 %0, %1, %2" : "=v"(r) : "v"(lo), "v"(hi));
  return r;
}

union U8 { unsigned u[4]; bf16x8 v; };

static __device__ __forceinline__ unsigned short f2bf(float f) {
  unsigned int u = __builtin_bit_cast(unsigned int, f);
  u += 0x7fffu + ((u >> 16) & 1u);
  return (unsigned short)(u >> 16);
}

// async global->LDS, 16B/lane; LDS dest is wave-uniform base (HW adds lane*16)
static __device__ __forceinline__ void dma16(const float* gsrc, void* ldst) {
  __builtin_amdgcn_global_load_lds(
      (const __attribute__((address_space(1))) unsigned int*)gsrc,
      (__attribute__((address_space(3))) unsigned int*)ldst, 16, 0, 0);
}

// H (bf16, 256B rows): byte-XOR swizzle key (R4-proven)
static __device__ __forceinline__ int swzh(int row) {
  return ((row & 8) << 1) | ((row & 6) << 5);
}

// ---- pre-pack all weights fp32 -> bf16 in MFMA B-fragment order ----
__global__ void pack_w(const float* __restrict__ Wt1, const float* __restrict__ Wa1,
                       const float* __restrict__ Wv1, const float* __restrict__ Wt2,
                       const float* __restrict__ Wa2, const float* __restrict__ Wv2,
                       unsigned short* __restrict__ pk) {
  int idx = blockIdx.x * 256 + threadIdx.x;
  if (idx >= 245760) return;
  float v;
  if (idx < 196608) {
    int j = idx & 7, l = (idx >> 3) & 63, ct = (idx >> 9) & 7, kt = (idx >> 12) & 15, e = idx >> 16;
    const float* W = (e == 0) ? Wt1 : (e == 1) ? Wa1 : Wv1;
    v = W[(kt * 32 + ((l >> 4) * 8) + j) * 128 + ct * 16 + (l & 15)];
  } else {
    int i2 = idx - 196608;
    int j = i2 & 7, l = (i2 >> 3) & 63, ct = (i2 >> 9) & 7, kt = (i2 >> 12) & 3, e = i2 >> 14;
    const float* W = (e == 0) ? Wt2 : (e == 1) ? Wa2 : Wv2;
    v = W[(kt * 32 + ((l >> 4) * 8) + j) * 128 + ct * 16 + (l & 15)];
  }
  pk[idx] = f2bf(v);
}

static __device__ __forceinline__ void stH(char* Hb, int g, int col, int rbase, f32x4 a) {
  #pragma unroll
  for (int rp = 0; rp < 2; ++rp) {
    int r0 = rbase + 4 * g + 2 * rp;
    unsigned p = cvtpk(fmaxf(a[2 * rp], 0.f), fmaxf(a[2 * rp + 1], 0.f));
    int a0 = r0 * 256 + ((((col >> 3) << 4)) ^ swzh(r0)) + (col & 7) * 2;
    int a1 = (r0 + 1) * 256 + ((((col >> 3) << 4)) ^ swzh(r0 + 1)) + (col & 7) * 2;
    *(unsigned short*)(Hb + a0) = (unsigned short)p;
    *(unsigned short*)(Hb + a1) = (unsigned short)(p >> 16);
  }
}

static __device__ __forceinline__ bf16x8 ldH(const char* hb, int row, int kt, int g) {
  return *(const bf16x8*)(hb + row * 256 + ((((kt * 4 + g) << 4)) ^ swzh(row)));
}

// Block: 32 rows x 128 cols, 256 thr (4 waves; wave w -> cols [32w,32w+32)).
// Layer-1 pipeline (m201-style): X fp32 via global_load_lds into a RING-4 of
// BK=64 chunks (depth-3 HBM prefetch); W-frags to REGISTERS prefetched one
// chunk ahead, issued BEFORE the X-DMAs each iter so the compiler's in-order
// W-wait retires only 2-iter-old DMAs; raw s_barrier + counted vmcnt(16) --
// loads stay in flight ACROSS barriers (never drain to 0 in the loop).
__global__ __launch_bounds__(256, 2) void mlp3(
    const float* __restrict__ X, const unsigned short* __restrict__ pk,
    const float* __restrict__ bt1, const float* __restrict__ bt2,
    const float* __restrict__ ba1, const float* __restrict__ ba2,
    const float* __restrict__ bv1, const float* __restrict__ bv2,
    float* __restrict__ out) {
  __shared__ float Xs[4 * 32 * 64];            // 32 KiB: ring-4 of 32r x 64c fp32
  __shared__ unsigned short H0[32 * 128];      // 8 KiB
  __shared__ unsigned short H1[32 * 128];      // 8 KiB
  const int t = threadIdx.x;
  const long brow = (long)blockIdx.x * 32;
  const int lane = t & 63;
  const int w = t >> 6;
  const int l15 = lane & 15;
  const int g = lane >> 4;

  // ---- routing flags -> mask, then fence (keep their waits before the pipeline)
  unsigned fmask = 0;
  #pragma unroll
  for (int rt = 0; rt < 2; ++rt)
    #pragma unroll
    for (int r = 0; r < 4; ++r) {
      float fv = X[(brow + rt * 16 + 4 * g + r) * 512 + 511];
      if (fv != 0.f) fmask |= 1u << (rt * 4 + r);
    }
  f32x4 at[2][2], aa[2][2], av[2][2];
  #pragma unroll
  for (int c = 0; c < 2; ++c) {
    float b0 = bt1[(2 * w + c) * 16 + l15];
    float b1v = ba1[(2 * w + c) * 16 + l15];
    float b2v = bv1[(2 * w + c) * 16 + l15];
    #pragma unroll
    for (int rt = 0; rt < 2; ++rt) {
      at[rt][c] = (f32x4){b0, b0, b0, b0};
      aa[rt][c] = (f32x4){b1v, b1v, b1v, b1v};
      av[rt][c] = (f32x4){b2v, b2v, b2v, b2v};
    }
  }
  asm volatile("" : "+v"(fmask));
  asm volatile("" ::: "memory");

  // ---- X staging: inverse-swizzled source, linear LDS dest ----
  // LDS layout: buf(8KB) = row*256B + phys16slot*16B; phys = logical ^ (row&7).
  // DMA lane: phys16 = lane&15, row = i*16 + w*4 + g  -> logical = (lane&15)^(row&7)
  const int drow0 = w * 4 + g;               // i=0 row; i=1 adds 16
  const int dkey = drow0 & 7;
  const int ds16 = (lane & 15) ^ dkey;       // logical 16B slot (4 floats)
  const float* __restrict__ dsrc0 = X + (brow + drow0) * 512 + ds16 * 4;
  auto stage = [&](int c) {
    char* db = (char*)Xs + (c & 3) * 8192 + w * 1024;
    dma16(dsrc0 + c * 64, db);
    dma16(dsrc0 + 16 * 512 + c * 64, db + 4096);
  };

  // ---- W-fragment register prefetch (ping-pong, static indices via unroll 2)
  bf16x8 wf[2][12];
  auto loadW = [&](bf16x8* d, int s) {
    #pragma unroll
    for (int ktl = 0; ktl < 2; ++ktl) {
      const int wo = (((2 * s + ktl) * 8 + 2 * w) << 9) + (lane << 3);
      #pragma unroll
      for (int e = 0; e < 3; ++e) {
        d[ktl * 6 + e * 2 + 0] = *(const bf16x8*)(pk + e * 65536 + wo);
        d[ktl * 6 + e * 2 + 1] = *(const bf16x8*)(pk + e * 65536 + wo + 512);
      }
    }
  };

  // ---- prologue: D0, W0, D1, D2 ; wait newer-than-D0 = 16 ----
  stage(0);
  loadW(wf[0], 0);
  asm volatile("" ::: "memory");
  stage(1);
  stage(2);
  asm volatile("s_waitcnt vmcnt(16)" ::: "memory");

  // A-frag read bases (2-way max by construction)
  const int abase = l15 * 256;
  const int akey = l15 & 7;

  // ---- layer-1: 8 chunks of BK=64, one raw barrier + vmcnt(16) each ----
  #pragma unroll 2
  for (int s = 0; s < 8; ++s) {
    const int p = s & 1;
    asm volatile("s_waitcnt vmcnt(16)\n\ts_barrier" ::: "memory");
    if (s < 7) loadW(wf[p ^ 1], s + 1);      // W first (older than D in queue)
    asm volatile("" ::: "memory");
    if (s < 5) stage(s + 3);                  // depth-3 X prefetch
    const char* xb = (const char*)Xs + (s & 3) * 8192;
    __builtin_amdgcn_s_setprio(1);
    #pragma unroll
    for (int ktl = 0; ktl < 2; ++ktl) {
      #pragma unroll
      for (int rt = 0; rt < 2; ++rt) {
        const int h0 = ((ktl * 4 + g) << 1);
        f32x4 f0 = *(const f32x4*)(xb + abase + rt * 4096 + ((h0 ^ akey) << 4));
        f32x4 f1 = *(const f32x4*)(xb + abase + rt * 4096 + (((h0 + 1) ^ akey) << 4));
        U8 u;
        u.u[0] = cvtpk(f0[0], f0[1]);
        u.u[1] = cvtpk(f0[2], f0[3]);
        u.u[2] = cvtpk(f1[0], f1[1]);
        u.u[3] = cvtpk(f1[2], f1[3]);
        at[rt][0] = __builtin_amdgcn_mfma_f32_16x16x32_bf16(u.v, wf[p][ktl * 6 + 0], at[rt][0], 0, 0, 0);
        at[rt][1] = __builtin_amdgcn_mfma_f32_16x16x32_bf16(u.v, wf[p][ktl * 6 + 1], at[rt][1], 0, 0, 0);
        aa[rt][0] = __builtin_amdgcn_mfma_f32_16x16x32_bf16(u.v, wf[p][ktl * 6 + 2], aa[rt][0], 0, 0, 0);
        aa[rt][1] = __builtin_amdgcn_mfma_f32_16x16x32_bf16(u.v, wf[p][ktl * 6 + 3], aa[rt][1], 0, 0, 0);
        av[rt][0] = __builtin_amdgcn_mfma_f32_16x16x32_bf16(u.v, wf[p][ktl * 6 + 4], av[rt][0], 0, 0, 0);
        av[rt][1] = __builtin_amdgcn_mfma_f32_16x16x32_bf16(u.v, wf[p][ktl * 6 + 5], av[rt][1], 0, 0, 0);
      }
    }
    __builtin_amdgcn_s_setprio(0);
  }

  // ---- relu + hidden tiles t->H0, a->H1 (full drain barriers fine from here) ----
  #pragma unroll
  for (int rt = 0; rt < 2; ++rt)
    #pragma unroll
    for (int c = 0; c < 2; ++c) {
      int col = (2 * w + c) * 16 + l15;
      stH((char*)H0, g, col, rt * 16, at[rt][c]);
      stH((char*)H1, g, col, rt * 16, aa[rt][c]);
    }
  __syncthreads();

  auto layer2 = [&](const unsigned short* Hb, int e, const float* __restrict__ b2,
                    f32x4 a2[2][2]) {
    #pragma unroll
    for (int c = 0; c < 2; ++c) {
      float bv = b2[(2 * w + c) * 16 + l15];
      a2[0][c] = (f32x4){bv, bv, bv, bv};
      a2[1][c] = (f32x4){bv, bv, bv, bv};
    }
    const unsigned short* W2f = pk + 196608 + e * 16384;
    __builtin_amdgcn_s_setprio(1);
    #pragma unroll
    for (int kt = 0; kt < 4; ++kt) {
      int wo = ((kt * 8 + 2 * w) << 9) + (lane << 3);
      bf16x8 w0 = *(const bf16x8*)(W2f + wo);
      bf16x8 w1 = *(const bf16x8*)(W2f + wo + 512);
      #pragma unroll
      for (int rt = 0; rt < 2; ++rt) {
        bf16x8 a = ldH((const char*)Hb, rt * 16 + l15, kt, g);
        a2[rt][0] = __builtin_amdgcn_mfma_f32_16x16x32_bf16(a, w0, a2[rt][0], 0, 0, 0);
        a2[rt][1] = __builtin_amdgcn_mfma_f32_16x16x32_bf16(a, w1, a2[rt][1], 0, 0, 0);
      }
    }
    __builtin_amdgcn_s_setprio(0);
  };

  f32x4 keep[2][2], a2[2][2];
  layer2(H0, 0, bt2, keep);    // transform
  layer2(H1, 1, ba2, a2);      // actor
  #pragma unroll
  for (int rt = 0; rt < 2; ++rt)
    #pragma unroll
    for (int c = 0; c < 2; ++c)
      #pragma unroll
      for (int r = 0; r < 4; ++r)
        if ((fmask >> (rt * 4 + r)) & 1u) keep[rt][c][r] = a2[rt][c][r];
  __syncthreads();             // t/a layer-2 reads done -> H0 reusable

  #pragma unroll
  for (int rt = 0; rt < 2; ++rt)
    #pragma unroll
    for (int c = 0; c < 2; ++c) {
      int col = (2 * w + c) * 16 + l15;
      stH((char*)H0, g, col, rt * 16, av[rt][c]);
    }
  __syncthreads();
  layer2(H0, 2, bv2, a2);      // value

  // ---- batched stores ----
  float* __restrict__ ov = out + NTOK * 128;
  #pragma unroll
  for (int rt = 0; rt < 2; ++rt)
    #pragma unroll
    for (int c = 0; c < 2; ++c)
      #pragma unroll
      for (int r = 0; r < 4; ++r) {
        long row = brow + rt * 16 + 4 * g + r;
        long col = (2 * w + c) * 16 + l15;
        out[row * 128 + col] = keep[rt][c][r];
        ov[row * 128 + col] = fmaxf(a2[rt][c][r], 0.f);
      }
}

extern "C" void kernel_launch(void* const* d_in, const int* in_sizes, int n_in,
                              void* d_out, int out_size, void* d_ws, size_t ws_size,
                              hipStream_t stream) {
  const float* X   = (const float*)d_in[0];
  const float* Wt1 = (const float*)d_in[1];
  const float* bt1 = (const float*)d_in[2];
  const float* Wt2 = (const float*)d_in[3];
  const float* bt2 = (const float*)d_in[4];
  const float* Wa1 = (const float*)d_in[5];
  const float* ba1 = (const float*)d_in[6];
  const float* Wa2 = (const float*)d_in[7];
  const float* ba2 = (const float*)d_in[8];
  const float* Wv1 = (const float*)d_in[9];
  const float* bv1 = (const float*)d_in[10];
  const float* Wv2 = (const float*)d_in[11];
  const float* bv2 = (const float*)d_in[12];
  unsigned short* pk = (unsigned short*)d_ws;   // 480 KiB packed weights

  pack_w<<<960, 256, 0, stream>>>(Wt1, Wa1, Wv1, Wt2, Wa2, Wv2, pk);
  mlp3<<<8192, 256, 0, stream>>>(X, pk, bt1, bt2, ba1, ba2, bv1, bv2, (float*)d_out);
}

// Round 12
// 286.952 us; speedup vs baseline: 2.1879x; 1.0597x over previous
//
#include <hip/hip_runtime.h>

#define NTOK 262144L

typedef __attribute__((ext_vector_type(4))) float f32x4;
typedef __attribute__((ext_vector_type(8))) short bf16x8;   // 8 x bf16 (4 VGPRs)

static __device__ __forceinline__ unsigned cvtpk(float lo, float hi) {
  unsigned r;
  asm("v_cvt_pk_bf16_f32 %0, %1, %2" : "=v"(r) : "v"(lo), "v"(hi));
  return r;
}

union U8 { unsigned u[4]; bf16x8 v; };

static __device__ __forceinline__ unsigned short f2bf(float f) {
  unsigned int u = __builtin_bit_cast(unsigned int, f);
  u += 0x7fffu + ((u >> 16) & 1u);
  return (unsigned short)(u >> 16);
}

// async global->LDS, 16B/lane; LDS dest = wave-uniform base + lane*16
static __device__ __forceinline__ void dma16(const float* gsrc, void* ldst) {
  __builtin_amdgcn_global_load_lds(
      (const __attribute__((address_space(1))) unsigned int*)gsrc,
      (__attribute__((address_space(3))) unsigned int*)ldst, 16, 0, 0);
}

// H (bf16, 256B rows): byte-XOR swizzle key (R4-proven)
static __device__ __forceinline__ int swzh(int row) {
  return ((row & 8) << 1) | ((row & 6) << 5);
}

// ---- pre-pack all weights fp32 -> bf16 in MFMA B-fragment order ----
// W1: [e][kt=16][ct=8][lane=64][j=8]  (k = kt*32 + (lane>>4)*8 + j, col = ct*16 + (lane&15))
// W2: [e][kt=4 ][ct=8][lane=64][j=8]
__global__ void pack_w(const float* __restrict__ Wt1, const float* __restrict__ Wa1,
                       const float* __restrict__ Wv1, const float* __restrict__ Wt2,
                       const float* __restrict__ Wa2, const float* __restrict__ Wv2,
                       unsigned short* __restrict__ pk) {
  int idx = blockIdx.x * 256 + threadIdx.x;
  if (idx >= 245760) return;
  float v;
  if (idx < 196608) {
    int j = idx & 7, l = (idx >> 3) & 63, ct = (idx >> 9) & 7, kt = (idx >> 12) & 15, e = idx >> 16;
    const float* W = (e == 0) ? Wt1 : (e == 1) ? Wa1 : Wv1;
    v = W[(kt * 32 + ((l >> 4) * 8) + j) * 128 + ct * 16 + (l & 15)];
  } else {
    int i2 = idx - 196608;
    int j = i2 & 7, l = (i2 >> 3) & 63, ct = (i2 >> 9) & 7, kt = (i2 >> 12) & 3, e = i2 >> 14;
    const float* W = (e == 0) ? Wt2 : (e == 1) ? Wa2 : Wv2;
    v = W[(kt * 32 + ((l >> 4) * 8) + j) * 128 + ct * 16 + (l & 15)];
  }
  pk[idx] = f2bf(v);
}

static __device__ __forceinline__ void stH(char* Hb, int g, int col, int rbase, f32x4 a) {
  #pragma unroll
  for (int rp = 0; rp < 2; ++rp) {
    int r0 = rbase + 4 * g + 2 * rp;
    unsigned p = cvtpk(fmaxf(a[2 * rp], 0.f), fmaxf(a[2 * rp + 1], 0.f));
    int a0 = r0 * 256 + ((((col >> 3) << 4)) ^ swzh(r0)) + (col & 7) * 2;
    int a1 = (r0 + 1) * 256 + ((((col >> 3) << 4)) ^ swzh(r0 + 1)) + (col & 7) * 2;
    *(unsigned short*)(Hb + a0) = (unsigned short)p;
    *(unsigned short*)(Hb + a1) = (unsigned short)(p >> 16);
  }
}

static __device__ __forceinline__ bf16x8 ldH(const char* hb, int row, int kt, int g) {
  return *(const bf16x8*)(hb + row * 256 + ((((kt * 4 + g) << 4)) ^ swzh(row)));
}

// Block: 64 rows x 128 cols, 512 thr = 8 waves.
// Wave w: row-half (w>>2)*32, col-quadrant cols [32*(w&3), +32) -- per-wave
// geometry IDENTICAL to R4 (rt=2, ct=2, acc 48 VGPR). Paired waves (w, w+4)
// load the SAME weight fragments -> L1 dedup; per-CU L2 weight traffic halves
// (32->16 blocks/CU x 480 KB). LDS 64 KiB -> 2 blocks/CU -> 16 waves/CU.
// X staged fp32 by global_load_lds, BK=64 double-buffer, stage-before-compute,
// plain __syncthreads (R4-proven discipline).
// Xs slot swizzle: phys16slot = logical ^ (row & 15)  (<=2-way on ds_read).
__global__ __launch_bounds__(512, 4) void mlp3(
    const float* __restrict__ X, const unsigned short* __restrict__ pk,
    const float* __restrict__ bt1, const float* __restrict__ bt2,
    const float* __restrict__ ba1, const float* __restrict__ ba2,
    const float* __restrict__ bv1, const float* __restrict__ bv2,
    float* __restrict__ out) {
  __shared__ float Xs[2 * 64 * 64];            // 32 KiB: dbuf 64r x 64c fp32
  __shared__ unsigned short H0[64 * 128];      // 16 KiB
  __shared__ unsigned short H1[64 * 128];      // 16 KiB
  const int t = threadIdx.x;
  const long brow = (long)blockIdx.x * 64;
  const int lane = t & 63;
  const int w = t >> 6;          // 0..7
  const int wq = w & 3;          // col quadrant
  const int rowoff = (w >> 2) * 32;   // row half
  const int l15 = lane & 15;
  const int g = lane >> 4;

  // ---- routing flags -> mask (rows this lane will store) ----
  unsigned fmask = 0;
  #pragma unroll
  for (int rt = 0; rt < 2; ++rt)
    #pragma unroll
    for (int r = 0; r < 4; ++r) {
      float fv = X[(brow + rowoff + rt * 16 + 4 * g + r) * 512 + 511];
      if (fv != 0.f) fmask |= 1u << (rt * 4 + r);
    }

  // ---- layer-1 accumulators, 3 experts (bias-init) ----
  f32x4 at[2][2], aa[2][2], av[2][2];
  #pragma unroll
  for (int c = 0; c < 2; ++c) {
    float b0 = bt1[(2 * wq + c) * 16 + l15];
    float b1v = ba1[(2 * wq + c) * 16 + l15];
    float b2v = bv1[(2 * wq + c) * 16 + l15];
    #pragma unroll
    for (int rt = 0; rt < 2; ++rt) {
      at[rt][c] = (f32x4){b0, b0, b0, b0};
      aa[rt][c] = (f32x4){b1v, b1v, b1v, b1v};
      av[rt][c] = (f32x4){b2v, b2v, b2v, b2v};
    }
  }

  // ---- DMA staging: wave covers rows [w*8, w*8+8) of the chunk (2 dma16) ----
  // lane l -> row w*8 + d*4 + (l>>4), phys slot l&15; source pre-swizzled.
  const int r0 = w * 8 + (lane >> 4);          // d=0 row; d=1 adds 4
  const float* __restrict__ s0 = X + (brow + r0) * 512 + (((lane & 15) ^ (r0 & 15)) << 2);
  const float* __restrict__ s1 = X + (brow + r0 + 4) * 512 + (((lane & 15) ^ ((r0 + 4) & 15)) << 2);
  auto stage = [&](int s) {
    char* db = (char*)Xs + (s & 1) * 16384 + w * 2048;
    dma16(s0 + s * 64, db);
    dma16(s1 + s * 64, db + 1024);
  };

  // ---- prologue: chunk 0 ----
  stage(0);
  __syncthreads();

  // ---- layer-1: 8 chunks of BK=64 ----
  #pragma unroll 2
  for (int s = 0; s < 8; ++s) {
    if (s < 7) stage(s + 1);     // issue next chunk's DMA before compute
    const char* xb = (const char*)Xs + (s & 1) * 16384;
    __builtin_amdgcn_s_setprio(1);
    #pragma unroll
    for (int ktl = 0; ktl < 2; ++ktl) {
      const int kt = 2 * s + ktl;
      const int wo = ((kt * 8 + 2 * wq) << 9) + (lane << 3);
      bf16x8 wt0 = *(const bf16x8*)(pk + wo);
      bf16x8 wt1v = *(const bf16x8*)(pk + wo + 512);
      bf16x8 wa0 = *(const bf16x8*)(pk + 65536 + wo);
      bf16x8 wa1v = *(const bf16x8*)(pk + 65536 + wo + 512);
      bf16x8 wv0 = *(const bf16x8*)(pk + 131072 + wo);
      bf16x8 wv1v = *(const bf16x8*)(pk + 131072 + wo + 512);
      #pragma unroll
      for (int rt = 0; rt < 2; ++rt) {
        const int row = rowoff + rt * 16 + l15;
        const int sl0 = (ktl * 8 + g * 2) ^ (row & 15);
        const int sl1 = (ktl * 8 + g * 2 + 1) ^ (row & 15);
        f32x4 f0 = *(const f32x4*)(xb + row * 256 + (sl0 << 4));
        f32x4 f1 = *(const f32x4*)(xb + row * 256 + (sl1 << 4));
        U8 u;
        u.u[0] = cvtpk(f0[0], f0[1]);
        u.u[1] = cvtpk(f0[2], f0[3]);
        u.u[2] = cvtpk(f1[0], f1[1]);
        u.u[3] = cvtpk(f1[2], f1[3]);
        at[rt][0] = __builtin_amdgcn_mfma_f32_16x16x32_bf16(u.v, wt0, at[rt][0], 0, 0, 0);
        at[rt][1] = __builtin_amdgcn_mfma_f32_16x16x32_bf16(u.v, wt1v, at[rt][1], 0, 0, 0);
        aa[rt][0] = __builtin_amdgcn_mfma_f32_16x16x32_bf16(u.v, wa0, aa[rt][0], 0, 0, 0);
        aa[rt][1] = __builtin_amdgcn_mfma_f32_16x16x32_bf16(u.v, wa1v, aa[rt][1], 0, 0, 0);
        av[rt][0] = __builtin_amdgcn_mfma_f32_16x16x32_bf16(u.v, wv0, av[rt][0], 0, 0, 0);
        av[rt][1] = __builtin_amdgcn_mfma_f32_16x16x32_bf16(u.v, wv1v, av[rt][1], 0, 0, 0);
      }
    }
    __builtin_amdgcn_s_setprio(0);
    __syncthreads();             // next chunk ready; old buffer consumable
  }

  // ---- relu + hidden tiles t->H0, a->H1 ----
  #pragma unroll
  for (int rt = 0; rt < 2; ++rt)
    #pragma unroll
    for (int c = 0; c < 2; ++c) {
      int col = (2 * wq + c) * 16 + l15;
      stH((char*)H0, g, col, rowoff + rt * 16, at[rt][c]);
      stH((char*)H1, g, col, rowoff + rt * 16, aa[rt][c]);
    }
  __syncthreads();

  // ---- layer 2 ----
  auto layer2 = [&](const unsigned short* Hb, int e, const float* __restrict__ b2,
                    f32x4 a2[2][2]) {
    #pragma unroll
    for (int c = 0; c < 2; ++c) {
      float bv = b2[(2 * wq + c) * 16 + l15];
      a2[0][c] = (f32x4){bv, bv, bv, bv};
      a2[1][c] = (f32x4){bv, bv, bv, bv};
    }
    const unsigned short* W2f = pk + 196608 + e * 16384;
    __builtin_amdgcn_s_setprio(1);
    #pragma unroll
    for (int kt = 0; kt < 4; ++kt) {
      int wo = ((kt * 8 + 2 * wq) << 9) + (lane << 3);
      bf16x8 w0 = *(const bf16x8*)(W2f + wo);
      bf16x8 w1 = *(const bf16x8*)(W2f + wo + 512);
      #pragma unroll
      for (int rt = 0; rt < 2; ++rt) {
        bf16x8 a = ldH((const char*)Hb, rowoff + rt * 16 + l15, kt, g);
        a2[rt][0] = __builtin_amdgcn_mfma_f32_16x16x32_bf16(a, w0, a2[rt][0], 0, 0, 0);
        a2[rt][1] = __builtin_amdgcn_mfma_f32_16x16x32_bf16(a, w1, a2[rt][1], 0, 0, 0);
      }
    }
    __builtin_amdgcn_s_setprio(0);
  };

  f32x4 keep[2][2], a2[2][2];
  layer2(H0, 0, bt2, keep);    // transform
  layer2(H1, 1, ba2, a2);      // actor
  #pragma unroll
  for (int rt = 0; rt < 2; ++rt)
    #pragma unroll
    for (int c = 0; c < 2; ++c)
      #pragma unroll
      for (int r = 0; r < 4; ++r)
        if ((fmask >> (rt * 4 + r)) & 1u) keep[rt][c][r] = a2[rt][c][r];
  __syncthreads();             // t/a layer-2 reads done -> H0 reusable

  #pragma unroll
  for (int rt = 0; rt < 2; ++rt)
    #pragma unroll
    for (int c = 0; c < 2; ++c) {
      int col = (2 * wq + c) * 16 + l15;
      stH((char*)H0, g, col, rowoff + rt * 16, av[rt][c]);
    }
  __syncthreads();
  layer2(H0, 2, bv2, a2);      // value

  // ---- batched stores ----
  float* __restrict__ ov = out + NTOK * 128;
  #pragma unroll
  for (int rt = 0; rt < 2; ++rt)
    #pragma unroll
    for (int c = 0; c < 2; ++c)
      #pragma unroll
      for (int r = 0; r < 4; ++r) {
        long row = brow + rowoff + rt * 16 + 4 * g + r;
        long col = (2 * wq + c) * 16 + l15;
        out[row * 128 + col] = keep[rt][c][r];
        ov[row * 128 + col] = fmaxf(a2[rt][c][r], 0.f);
      }
}

extern "C" void kernel_launch(void* const* d_in, const int* in_sizes, int n_in,
                              void* d_out, int out_size, void* d_ws, size_t ws_size,
                              hipStream_t stream) {
  const float* X   = (const float*)d_in[0];
  const float* Wt1 = (const float*)d_in[1];
  const float* bt1 = (const float*)d_in[2];
  const float* Wt2 = (const float*)d_in[3];
  const float* bt2 = (const float*)d_in[4];
  const float* Wa1 = (const float*)d_in[5];
  const float* ba1 = (const float*)d_in[6];
  const float* Wa2 = (const float*)d_in[7];
  const float* ba2 = (const float*)d_in[8];
  const float* Wv1 = (const float*)d_in[9];
  const float* bv1 = (const float*)d_in[10];
  const float* Wv2 = (const float*)d_in[11];
  const float* bv2 = (const float*)d_in[12];
  unsigned short* pk = (unsigned short*)d_ws;   // 480 KiB packed weights

  pack_w<<<960, 256, 0, stream>>>(Wt1, Wa1, Wv1, Wt2, Wa2, Wv2, pk);
  mlp3<<<4096, 512, 0, stream>>>(X, pk, bt1, bt2, ba1, ba2, bv1, bv2, (float*)d_out);
}